// Round 1
// baseline (537.182 us; speedup 1.0000x reference)
//
#include <hip/hip_runtime.h>
#include <math.h>

// GateFusion: out = (1-g)*x_c@W_c + g*x_d@W_d,  g = sigmoid(relu(LN(concat@Wg1))@Wg2)
// fp32 register-tiled baseline. 64-row tiles in LDS, gate folded into staged x.

namespace {
constexpr int CD = 64;    // detail channels
constexpr int CC = 96;    // context channels
constexpr int CK = 160;   // CD + CC
constexpr int CH = 64;    // gate hidden (CF/2)
constexpr int CF = 128;   // output channels
constexpr int BM = 64;    // rows per block
constexpr int XS_LD = 164; // padded row stride in floats (656 B = 41*16, 16B-aligned)

__global__ __launch_bounds__(256)
void gate_fusion_f32(const float* __restrict__ xd,
                     const float* __restrict__ xc,
                     const float* __restrict__ Wd,
                     const float* __restrict__ Wc,
                     const float* __restrict__ Wg1,
                     const float* __restrict__ gma,
                     const float* __restrict__ bta,
                     const float* __restrict__ Wg2,
                     float* __restrict__ out,
                     int N) {
  __shared__ float xs[BM * XS_LD];
  __shared__ float gs[BM];
  const int tid = threadIdx.x;
  const int r0  = blockIdx.x * BM;

  // ---- stage x tile into LDS: xs[r][0:64]=x_d row, xs[r][64:160]=x_c row.
  // Tile rows are consecutive, so each source tile is one contiguous span.
  {
    const int totD  = N * CD;
    const int base4 = r0 * CD / 4;
    #pragma unroll
    for (int it = 0; it < (BM * CD / 4) / 256; ++it) {   // 4 iters
      const int i  = tid + it * 256;
      const int gi = base4 + i;
      float4 v = make_float4(0.f, 0.f, 0.f, 0.f);
      if (gi * 4 + 3 < totD) v = reinterpret_cast<const float4*>(xd)[gi];
      const int r = (i * 4) / CD, c = (i * 4) % CD;
      *reinterpret_cast<float4*>(&xs[r * XS_LD + c]) = v;
    }
    const int totC  = N * CC;
    const int basc4 = r0 * CC / 4;
    #pragma unroll
    for (int it = 0; it < (BM * CC / 4) / 256; ++it) {   // 6 iters
      const int i  = tid + it * 256;
      const int gi = basc4 + i;
      float4 v = make_float4(0.f, 0.f, 0.f, 0.f);
      if (gi * 4 + 3 < totC) v = reinterpret_cast<const float4*>(xc)[gi];
      const int r = (i * 4) / CC, c = (i * 4) % CC;
      *reinterpret_cast<float4*>(&xs[r * XS_LD + CD + c]) = v;
    }
  }
  __syncthreads();

  // ---- phase 1: h = concat @ Wg1 [BM x 64]; thread = 4 rows x 4 cols
  const int cg = tid & 15;   // cols cg*4 .. cg*4+3
  const int rg = tid >> 4;   // rows rg*4 .. rg*4+3
  float acc[4][4];
  #pragma unroll
  for (int i = 0; i < 4; ++i)
    #pragma unroll
    for (int j = 0; j < 4; ++j) acc[i][j] = 0.f;

  #pragma unroll 2
  for (int k = 0; k < CK; k += 4) {
    float w[4][4];
    #pragma unroll
    for (int q = 0; q < 4; ++q)
      *reinterpret_cast<float4*>(w[q]) =
          *reinterpret_cast<const float4*>(&Wg1[(k + q) * CH + cg * 4]);
    #pragma unroll
    for (int i = 0; i < 4; ++i) {
      float xv[4];
      *reinterpret_cast<float4*>(xv) =
          *reinterpret_cast<const float4*>(&xs[(rg * 4 + i) * XS_LD + k]);
      #pragma unroll
      for (int j = 0; j < 4; ++j)
        acc[i][j] += xv[0] * w[0][j] + xv[1] * w[1][j] +
                     xv[2] * w[2][j] + xv[3] * w[3][j];
    }
  }

  // ---- LayerNorm + relu + gate (reduce across the 16-lane col group)
  float g4[4], b4[4], w2[4];
  *reinterpret_cast<float4*>(g4) = *reinterpret_cast<const float4*>(&gma[cg * 4]);
  *reinterpret_cast<float4*>(b4) = *reinterpret_cast<const float4*>(&bta[cg * 4]);
  *reinterpret_cast<float4*>(w2) = *reinterpret_cast<const float4*>(&Wg2[cg * 4]);

  #pragma unroll
  for (int i = 0; i < 4; ++i) {
    float s = 0.f, q = 0.f;
    #pragma unroll
    for (int j = 0; j < 4; ++j) { s += acc[i][j]; q += acc[i][j] * acc[i][j]; }
    #pragma unroll
    for (int m = 1; m < 16; m <<= 1) {
      s += __shfl_xor(s, m, 64);
      q += __shfl_xor(q, m, 64);
    }
    const float mu  = s * (1.f / CH);
    const float var = q * (1.f / CH) - mu * mu;
    const float rsd = rsqrtf(var + 1e-5f);
    float p = 0.f;
    #pragma unroll
    for (int j = 0; j < 4; ++j) {
      const float h = fmaxf((acc[i][j] - mu) * rsd * g4[j] + b4[j], 0.f);
      p += h * w2[j];
    }
    #pragma unroll
    for (int m = 1; m < 16; m <<= 1) p += __shfl_xor(p, m, 64);
    const float gate = 1.f / (1.f + expf(-p));
    if (cg == 0) gs[rg * 4 + i] = gate;
  }
  __syncthreads();

  // ---- fold gate into staged x: x_d *= g, x_c *= (1-g)
  {
    const int r  = tid >> 2;          // 4 threads per row
    const int c0 = (tid & 3) * 40;    // 40 cols each (10 float4)
    const float g  = gs[r];
    const float gm = 1.f - g;
    #pragma unroll
    for (int c4 = 0; c4 < 10; ++c4) {
      const int c = c0 + c4 * 4;      // quad never straddles col 64 (64%4==0)
      const float sc = (c < CD) ? g : gm;
      float4* p4 = reinterpret_cast<float4*>(&xs[r * XS_LD + c]);
      float4 v = *p4;
      v.x *= sc; v.y *= sc; v.z *= sc; v.w *= sc;
      *p4 = v;
    }
  }
  __syncthreads();

  // ---- phase 2: out = xs_scaled @ [Wd; Wc]; thread = 8 rows x 4 cols
  const int cg2 = tid & 31;  // cols cg2*4 .. +3
  const int rg2 = tid >> 5;  // rows rg2*8 .. +7
  float a2[8][4];
  #pragma unroll
  for (int i = 0; i < 8; ++i)
    #pragma unroll
    for (int j = 0; j < 4; ++j) a2[i][j] = 0.f;

  #pragma unroll 2
  for (int k = 0; k < CD; k += 4) {
    float w[4][4];
    #pragma unroll
    for (int q = 0; q < 4; ++q)
      *reinterpret_cast<float4*>(w[q]) =
          *reinterpret_cast<const float4*>(&Wd[(k + q) * CF + cg2 * 4]);
    #pragma unroll
    for (int i = 0; i < 8; ++i) {
      float xv[4];
      *reinterpret_cast<float4*>(xv) =
          *reinterpret_cast<const float4*>(&xs[(rg2 * 8 + i) * XS_LD + k]);
      #pragma unroll
      for (int j = 0; j < 4; ++j)
        a2[i][j] += xv[0] * w[0][j] + xv[1] * w[1][j] +
                    xv[2] * w[2][j] + xv[3] * w[3][j];
    }
  }
  #pragma unroll 2
  for (int k = 0; k < CC; k += 4) {
    float w[4][4];
    #pragma unroll
    for (int q = 0; q < 4; ++q)
      *reinterpret_cast<float4*>(w[q]) =
          *reinterpret_cast<const float4*>(&Wc[(k + q) * CF + cg2 * 4]);
    #pragma unroll
    for (int i = 0; i < 8; ++i) {
      float xv[4];
      *reinterpret_cast<float4*>(xv) =
          *reinterpret_cast<const float4*>(&xs[(rg2 * 8 + i) * XS_LD + CD + k]);
      #pragma unroll
      for (int j = 0; j < 4; ++j)
        a2[i][j] += xv[0] * w[0][j] + xv[1] * w[1][j] +
                    xv[2] * w[2][j] + xv[3] * w[3][j];
    }
  }

  #pragma unroll
  for (int i = 0; i < 8; ++i) {
    const int r = r0 + rg2 * 8 + i;
    if (r < N) {
      float4 v = make_float4(a2[i][0], a2[i][1], a2[i][2], a2[i][3]);
      *reinterpret_cast<float4*>(&out[r * CF + cg2 * 4]) = v;
    }
  }
}
} // namespace

extern "C" void kernel_launch(void* const* d_in, const int* in_sizes, int n_in,
                              void* d_out, int out_size, void* d_ws, size_t ws_size,
                              hipStream_t stream) {
  const float* xd  = (const float*)d_in[0];
  const float* xc  = (const float*)d_in[1];
  const float* Wd  = (const float*)d_in[2];
  const float* Wc  = (const float*)d_in[3];
  const float* Wg1 = (const float*)d_in[4];
  const float* gma = (const float*)d_in[5];
  const float* bta = (const float*)d_in[6];
  const float* Wg2 = (const float*)d_in[7];
  float* out = (float*)d_out;

  const int N = in_sizes[0] / CD;
  const int nblk = (N + BM - 1) / BM;
  gate_fusion_f32<<<dim3(nblk), dim3(256), 0, stream>>>(
      xd, xc, Wd, Wc, Wg1, gma, bta, Wg2, out, N);
}

// Round 2
// 152.528 us; speedup vs baseline: 3.5219x; 3.5219x over previous
//
#include <hip/hip_runtime.h>
#include <hip/hip_bf16.h>
#include <math.h>

// GateFusion via bf16 MFMA (16x16x32), all-register, no LDS, no barriers.
// out = g * (x_d@W_d) + (1-g) * (x_c@W_c),
// g = sigmoid( relu(LN(concat@Wg1)) @ Wg2 ),  per row.
//
// d_ws holds pre-converted fragment-linear bf16 weights:
//   frags 0..19 : Wg1  (ks 0..4) x (nt 0..3)   [K=160, N=64]
//   frags 20..59: [Wd;Wc] (ks 0..4) x (nt 0..7) [K=160, N=128]
// Each frag = 512 bf16 (1 KB): lane l holds B[k0+j][n], k0=ks*32+(l>>4)*8,
// n = nt*16 + (l&15), j=0..7  -> stored at frag*512 + l*8.

namespace {

typedef __attribute__((ext_vector_type(8))) short short8;
typedef __attribute__((ext_vector_type(4))) float f32x4;

constexpr int CD = 64, CC = 96, CH = 64, CF = 128;
constexpr int NFG1 = 20;   // gate-weight frags
constexpr int NFCB = 40;   // combined-output-weight frags

__device__ inline short bf16_of(float f) {
  __hip_bfloat16 h = __float2bfloat16(f);
  return *reinterpret_cast<short*>(&h);
}

__global__ void convert_weights(const float* __restrict__ Wd,
                                const float* __restrict__ Wc,
                                const float* __restrict__ Wg1,
                                short* __restrict__ ws) {
  const int t = blockIdx.x * 256 + threadIdx.x;
  if (t >= 64 * (NFG1 + NFCB)) return;
  const int frag = t >> 6, l = t & 63;
  const int cidx = l & 15, kb = l >> 4;
  float v[8];
  if (frag < NFG1) {
    const int ks = frag >> 2, nt = frag & 3;
    const int n = nt * 16 + cidx, k0 = ks * 32 + kb * 8;
    #pragma unroll
    for (int j = 0; j < 8; ++j) v[j] = Wg1[(k0 + j) * CH + n];
  } else {
    const int f2 = frag - NFG1;
    const int ks = f2 >> 3, nt = f2 & 7;
    const int n = nt * 16 + cidx, k0 = ks * 32 + kb * 8;
    #pragma unroll
    for (int j = 0; j < 8; ++j) {
      const int k = k0 + j;
      v[j] = (k < CD) ? Wd[k * CF + n] : Wc[(k - CD) * CF + n];
    }
  }
  short8 o;
  #pragma unroll
  for (int j = 0; j < 8; ++j) o[j] = bf16_of(v[j]);
  *reinterpret_cast<short8*>(ws + frag * 512 + l * 8) = o;
}

__global__ __launch_bounds__(256)
void gate_fusion_mfma(const float* __restrict__ xd,
                      const float* __restrict__ xc,
                      const float* __restrict__ gma,
                      const float* __restrict__ bta,
                      const float* __restrict__ Wg2,
                      const short* __restrict__ wf,
                      float* __restrict__ out, int N) {
  const int lane = threadIdx.x & 63;
  const int wv   = threadIdx.x >> 6;
  const int r0   = (blockIdx.x * 4 + wv) * 32;   // this wave's 32-row start
  if (r0 >= N) return;                            // N % 32 == 0: whole-wave granularity
  const int cidx = lane & 15;
  const int kb   = lane >> 4;

  // ---- load x as A-fragments (bf16), kept in registers for both GEMMs
  short8 xf[2][5];
  #pragma unroll
  for (int mt = 0; mt < 2; ++mt) {
    const size_t row = (size_t)(r0 + mt * 16 + cidx);
    const float* rd = xd + row * CD;
    const float* rc = xc + row * CC;
    #pragma unroll
    for (int ks = 0; ks < 5; ++ks) {
      const int k0 = ks * 32 + kb * 8;           // frag never straddles k=64
      const float* p = (k0 < CD) ? (rd + k0) : (rc + (k0 - CD));
      f32x4 a = *reinterpret_cast<const f32x4*>(p);
      f32x4 b = *reinterpret_cast<const f32x4*>(p + 4);
      short8 f;
      #pragma unroll
      for (int j = 0; j < 4; ++j) { f[j] = bf16_of(a[j]); f[4 + j] = bf16_of(b[j]); }
      xf[mt][ks] = f;
    }
  }

  // ---- phase 1: h = concat @ Wg1  [32 x 64]
  const f32x4 vzero = {0.f, 0.f, 0.f, 0.f};
  f32x4 acc1[2][4];
  #pragma unroll
  for (int mt = 0; mt < 2; ++mt)
    #pragma unroll
    for (int nt = 0; nt < 4; ++nt) acc1[mt][nt] = vzero;

  #pragma unroll
  for (int ks = 0; ks < 5; ++ks) {
    short8 bg[4];
    #pragma unroll
    for (int nt = 0; nt < 4; ++nt)
      bg[nt] = *reinterpret_cast<const short8*>(wf + (ks * 4 + nt) * 512 + lane * 8);
    #pragma unroll
    for (int mt = 0; mt < 2; ++mt)
      #pragma unroll
      for (int nt = 0; nt < 4; ++nt)
        acc1[mt][nt] = __builtin_amdgcn_mfma_f32_16x16x32_bf16(
            xf[mt][ks], bg[nt], acc1[mt][nt], 0, 0, 0);
  }

  // ---- LayerNorm + relu + dot(Wg2) + sigmoid, in C-fragment layout
  float gmv[4], btv[4], w2v[4];
  #pragma unroll
  for (int nt = 0; nt < 4; ++nt) {
    const int c = nt * 16 + cidx;
    gmv[nt] = gma[c]; btv[nt] = bta[c]; w2v[nt] = Wg2[c];
  }
  float gate[2][4];
  #pragma unroll
  for (int mt = 0; mt < 2; ++mt) {
    float s[4], q[4];
    #pragma unroll
    for (int r = 0; r < 4; ++r) {
      s[r] = 0.f; q[r] = 0.f;
      #pragma unroll
      for (int nt = 0; nt < 4; ++nt) {
        const float c = acc1[mt][nt][r];
        s[r] += c; q[r] += c * c;
      }
    }
    #pragma unroll
    for (int m = 1; m < 16; m <<= 1)
      #pragma unroll
      for (int r = 0; r < 4; ++r) {
        s[r] += __shfl_xor(s[r], m, 64);
        q[r] += __shfl_xor(q[r], m, 64);
      }
    float p[4];
    #pragma unroll
    for (int r = 0; r < 4; ++r) {
      const float mu  = s[r] * (1.f / CH);
      const float var = q[r] * (1.f / CH) - mu * mu;
      const float rsd = rsqrtf(var + 1e-5f);
      float pp = 0.f;
      #pragma unroll
      for (int nt = 0; nt < 4; ++nt) {
        const float h = fmaxf((acc1[mt][nt][r] - mu) * rsd * gmv[nt] + btv[nt], 0.f);
        pp += h * w2v[nt];
      }
      p[r] = pp;
    }
    #pragma unroll
    for (int m = 1; m < 16; m <<= 1)
      #pragma unroll
      for (int r = 0; r < 4; ++r) p[r] += __shfl_xor(p[r], m, 64);
    #pragma unroll
    for (int r = 0; r < 4; ++r) gate[mt][r] = 1.f / (1.f + expf(-p[r]));
  }

  // ---- phase 2: dual-accumulate detail (ks 0..1) / context (ks 2..4),
  //      split into two nt-halves to cap register pressure
  const short* wcb = wf + NFG1 * 512;
  #pragma unroll
  for (int h = 0; h < 2; ++h) {
    f32x4 aD[2][4], aC[2][4];
    #pragma unroll
    for (int mt = 0; mt < 2; ++mt)
      #pragma unroll
      for (int nt = 0; nt < 4; ++nt) { aD[mt][nt] = vzero; aC[mt][nt] = vzero; }

    #pragma unroll
    for (int ks = 0; ks < 5; ++ks) {
      short8 bg[4];
      #pragma unroll
      for (int nt = 0; nt < 4; ++nt)
        bg[nt] = *reinterpret_cast<const short8*>(
            wcb + (ks * 8 + h * 4 + nt) * 512 + lane * 8);
      if (ks < 2) {
        #pragma unroll
        for (int mt = 0; mt < 2; ++mt)
          #pragma unroll
          for (int nt = 0; nt < 4; ++nt)
            aD[mt][nt] = __builtin_amdgcn_mfma_f32_16x16x32_bf16(
                xf[mt][ks], bg[nt], aD[mt][nt], 0, 0, 0);
      } else {
        #pragma unroll
        for (int mt = 0; mt < 2; ++mt)
          #pragma unroll
          for (int nt = 0; nt < 4; ++nt)
            aC[mt][nt] = __builtin_amdgcn_mfma_f32_16x16x32_bf16(
                xf[mt][ks], bg[nt], aC[mt][nt], 0, 0, 0);
      }
    }

    // epilogue: blend with per-row gate (already in C-row layout)
    #pragma unroll
    for (int mt = 0; mt < 2; ++mt) {
      const size_t rowb = (size_t)(r0 + mt * 16 + kb * 4);
      #pragma unroll
      for (int nt = 0; nt < 4; ++nt) {
        #pragma unroll
        for (int r = 0; r < 4; ++r) {
          const float g = gate[mt][r];
          const float o = g * aD[mt][nt][r] + (1.f - g) * aC[mt][nt][r];
          out[(rowb + r) * CF + (h * 4 + nt) * 16 + cidx] = o;
        }
      }
    }
  }
}

}  // namespace

extern "C" void kernel_launch(void* const* d_in, const int* in_sizes, int n_in,
                              void* d_out, int out_size, void* d_ws, size_t ws_size,
                              hipStream_t stream) {
  const float* xd  = (const float*)d_in[0];
  const float* xc  = (const float*)d_in[1];
  const float* Wd  = (const float*)d_in[2];
  const float* Wc  = (const float*)d_in[3];
  const float* Wg1 = (const float*)d_in[4];
  const float* gma = (const float*)d_in[5];
  const float* bta = (const float*)d_in[6];
  const float* Wg2 = (const float*)d_in[7];
  float* out = (float*)d_out;
  short* ws  = (short*)d_ws;   // needs 60 KB

  const int N = in_sizes[0] / CD;

  convert_weights<<<dim3(15), dim3(256), 0, stream>>>(Wd, Wc, Wg1, ws);

  const int nblk = (N + 127) / 128;
  gate_fusion_mfma<<<dim3(nblk), dim3(256), 0, stream>>>(
      xd, xc, gma, bta, Wg2, ws, out, N);
}